// Round 21
// baseline (559.535 us; speedup 1.0000x reference)
//
#include <hip/hip_runtime.h>
#include <hip/hip_bf16.h>
#include <math.h>

#define NN 100000
#define NE 1600000
#define KIN 128
#define HD 64
#define NC 10
#define NL 4
#define NG 200
#define NBKT 196     // buckets of 512 nodes: bucket = dst >> 9
#define MAXIDX 2560  // LDS edge-index slab (gather)
#define SORTCAP 12288  // LDS sort buffer (mean 8192/bucket, +45 sigma)
#define SB 32        // coarse sort buckets (src>>12: 0..24 used)
#define ZCNT (5 * NG * HD + NL * 256 + 256)  // zero span (floats)

typedef short s16x8 __attribute__((ext_vector_type(8)));
typedef float f32x4 __attribute__((ext_vector_type(4)));
using f4 = float4;

static __device__ __forceinline__ ushort f2bf(float x) {
  __hip_bfloat16 b = __float2bfloat16(x);
  return *reinterpret_cast<ushort*>(&b);
}
static __device__ __forceinline__ float bf2f(ushort u) {
  return __uint_as_float(((unsigned)u) << 16);
}
static __device__ __forceinline__ s16x8 zero8() {
  s16x8 v;
#pragma unroll
  for (int i = 0; i < 8; ++i) v[i] = 0;
  return v;
}

// ---------- prologue: pack weights (blocks 0-9) + zero accum (blocks 10+) ---
__global__ __launch_bounds__(256) void prologue_kernel(
    const float* __restrict__ Wemb, const float* __restrict__ W1,
    const float* __restrict__ W2, ushort* __restrict__ Wpk,
    float* __restrict__ zbase) {
  int b = blockIdx.x;
  if (b < 10) {
    const float* src = (b < 2)   ? Wemb + b * 4096
                       : (b < 6) ? W1 + (b - 2) * 4096
                                 : W2 + (b - 6) * 4096;
    for (int idx = threadIdx.x; idx < 4096; idx += 256) {
      int k = idx >> 6, n = idx & 63;
      int dsti = ((k >> 5) * 4 + (n >> 4)) * 512 +
                 (((k >> 3) & 3) * 16 + (n & 15)) * 8 + (k & 7);
      Wpk[b * 4096 + dsti] = f2bf(src[idx]);
    }
  } else {
    int nz = (gridDim.x - 10) * 256;
    f4 z = make_float4(0.f, 0.f, 0.f, 0.f);
    for (int i = (b - 10) * 256 + threadIdx.x; i < ZCNT / 4; i += nz)
      *reinterpret_cast<f4*>(&zbase[i * 4]) = z;
  }
}

// ======================= CSR build via 2-level counting sort ================
__global__ __launch_bounds__(256) void bucket_hist(const int* __restrict__ dst,
                                                   int* __restrict__ gbucket) {
  __shared__ int lh[NBKT];
  int tid = threadIdx.x;
  for (int i = tid; i < NBKT; i += 256) lh[i] = 0;
  __syncthreads();
  int base = blockIdx.x * 4096;
#pragma unroll 4
  for (int it = 0; it < 16; ++it) {
    int e = base + it * 256 + tid;
    if (e < NE) atomicAdd(&lh[dst[e] >> 9], 1);
  }
  __syncthreads();
  for (int i = tid; i < NBKT; i += 256)
    if (lh[i]) atomicAdd(&gbucket[i], lh[i]);
}

__global__ __launch_bounds__(256) void bucket_scan(const int* __restrict__ gbucket,
                                                   int* __restrict__ bbase,
                                                   int* __restrict__ bcur) {
  __shared__ int s[256];
  int tid = threadIdx.x;
  int v = (tid < NBKT) ? gbucket[tid] : 0;
  s[tid] = v;
  __syncthreads();
  for (int off = 1; off < 256; off <<= 1) {
    int t = (tid >= off) ? s[tid - off] : 0;
    __syncthreads();
    s[tid] += t;
    __syncthreads();
  }
  int excl = s[tid] - v;
  if (tid <= NBKT) bbase[tid] = excl;
  if (tid < NBKT) bcur[tid] = excl;
}

__global__ __launch_bounds__(256) void bucket_scatter(const int* __restrict__ src,
                                                      const int* __restrict__ dst,
                                                      int* __restrict__ bcur,
                                                      int2* __restrict__ pairs) {
  __shared__ int lh[NBKT];
  __shared__ int lbase[NBKT];
  int tid = threadIdx.x;
  for (int i = tid; i < NBKT; i += 256) lh[i] = 0;
  __syncthreads();
  int base = blockIdx.x * 4096;
  int dloc[16], sloc[16];
#pragma unroll
  for (int it = 0; it < 16; ++it) {
    int e = base + it * 256 + tid;
    bool ok = e < NE;
    dloc[it] = ok ? dst[e] : -1;
    sloc[it] = ok ? src[e] : 0;
    if (ok) atomicAdd(&lh[dloc[it] >> 9], 1);
  }
  __syncthreads();
  for (int i = tid; i < NBKT; i += 256) {
    int c = lh[i];
    lbase[i] = c ? atomicAdd(&bcur[i], c) : 0;
    lh[i] = 0;
  }
  __syncthreads();
#pragma unroll
  for (int it = 0; it < 16; ++it) {
    int d = dloc[it];
    if (d >= 0) {
      int b = d >> 9;
      int p = lbase[b] + atomicAdd(&lh[b], 1);
      pairs[p] = make_int2(d, sloc[it]);
    }
  }
}

// builds row_ptr/csr_src; neighbor lists COARSELY sorted by src>>12 via
// per-row counting sort (register counters, O(d) passes, no dep chains).
__global__ __launch_bounds__(256) void csr_build(const int2* __restrict__ pairs,
                                                 const int* __restrict__ bbase,
                                                 int* __restrict__ row_ptr,
                                                 int* __restrict__ csr_src) {
  __shared__ int deg[512];
  __shared__ int psum[256];
  __shared__ int cur[512];
  __shared__ int srt[SORTCAP];
  int b = blockIdx.x;
  int tid = threadIdx.x;
  int beg = bbase[b], end = bbase[b + 1];
  int cnt = end - beg;
  int node0 = b << 9;
  deg[tid] = 0;
  deg[tid + 256] = 0;
  __syncthreads();
  for (int i = beg + tid; i < end; i += 256)
    atomicAdd(&deg[pairs[i].x - node0], 1);
  __syncthreads();
  int a0 = deg[2 * tid], a1 = deg[2 * tid + 1];
  psum[tid] = a0 + a1;
  __syncthreads();
  for (int off = 1; off < 256; off <<= 1) {
    int t = (tid >= off) ? psum[tid - off] : 0;
    __syncthreads();
    psum[tid] += t;
    __syncthreads();
  }
  int pe = psum[tid] - (a0 + a1);
  int e0 = pe, e1 = pe + a0;  // local (beg-relative) row starts
  cur[2 * tid] = e0;
  cur[2 * tid + 1] = e1;
  int n0 = node0 + 2 * tid, n1 = node0 + 2 * tid + 1;
  if (n0 < NN) row_ptr[n0] = beg + e0;
  if (n1 < NN) row_ptr[n1] = beg + e1;
  __syncthreads();

  if (cnt <= SORTCAP) {
    // scatter into LDS (local positions)
    for (int i = beg + tid; i < end; i += 256) {
      int2 pr = pairs[i];
      int p = atomicAdd(&cur[pr.x - node0], 1);
      srt[p] = pr.y;
    }
    __syncthreads();
    // coarse counting sort per owned row: bucket = src>>12 (0.5MB window)
#pragma unroll
    for (int rr = 0; rr < 2; ++rr) {
      int s0 = (rr == 0) ? e0 : e1;
      int d0 = (rr == 0) ? a0 : a1;
      int ofs[SB];
#pragma unroll
      for (int q = 0; q < SB; ++q) ofs[q] = 0;
      for (int i = 0; i < d0; ++i) {
        int bkt = srt[s0 + i] >> 12;
#pragma unroll
        for (int q = 0; q < SB; ++q) ofs[q] += (bkt == q) ? 1 : 0;
      }
      // exclusive prefix in registers
      int run = 0;
#pragma unroll
      for (int q = 0; q < SB; ++q) {
        int c = ofs[q];
        ofs[q] = run;
        run += c;
      }
      // stable placement (direct to global)
      for (int i = 0; i < d0; ++i) {
        int key = srt[s0 + i];
        int bkt = key >> 12;
        int pos = 0;
#pragma unroll
        for (int q = 0; q < SB; ++q)
          if (bkt == q) pos = ofs[q];
        csr_src[beg + s0 + pos] = key;
#pragma unroll
        for (int q = 0; q < SB; ++q) ofs[q] += (bkt == q) ? 1 : 0;
      }
    }
  } else {
    // fallback (statistically unreachable): global scatter, unsorted
    for (int i = beg + tid; i < end; i += 256) {
      int2 pr = pairs[i];
      int p = atomicAdd(&cur[pr.x - node0], 1);
      csr_src[beg + p] = pr.y;
    }
  }
  if (b == 0 && tid == 0) row_ptr[NN] = NE;
}

// ------- embed GEMM + fused layer-0 pooling (pool from LDS tile) ------------
__global__ __launch_bounds__(256, 4) void embed_kernel(
    const float* __restrict__ X, const ushort* __restrict__ wt,
    const float* __restrict__ bias, const int* __restrict__ gid,
    ushort* __restrict__ hbf, float* __restrict__ pooled0) {
  __shared__ ushort lds_a[128 * 64];
  __shared__ ushort lds_b[4096];

  const int tid = threadIdx.x;
  const int row0 = blockIdx.x * 128;
  const int w = tid >> 6;
  const int l = tid & 63;
  const int lr = l >> 4, lc = l & 15;

  f32x4 acc[2][4];
#pragma unroll
  for (int mi = 0; mi < 2; ++mi)
#pragma unroll
    for (int nf = 0; nf < 4; ++nf)
#pragma unroll
      for (int r = 0; r < 4; ++r) acc[mi][nf][r] = 0.f;

  for (int kt = 0; kt < 2; ++kt) {
    if (kt) __syncthreads();
#pragma unroll
    for (int i = 0; i < 2; ++i) {
      int ch = i * 256 + tid;
      *reinterpret_cast<s16x8*>(&lds_b[ch * 8]) =
          *reinterpret_cast<const s16x8*>(&wt[kt * 4096 + ch * 8]);
    }
#pragma unroll
    for (int i = 0; i < 4; ++i) {
      int f8i = i * 256 + tid;
      int row = f8i >> 3, c8 = f8i & 7;
      int grow = row0 + row;
      s16x8 val = zero8();
      if (grow < NN) {
        const float* p = X + (size_t)grow * KIN + kt * 64 + c8 * 8;
        f4 x0 = *reinterpret_cast<const f4*>(p);
        f4 x1 = *reinterpret_cast<const f4*>(p + 4);
        float xv[8] = {x0.x, x0.y, x0.z, x0.w, x1.x, x1.y, x1.z, x1.w};
#pragma unroll
        for (int j = 0; j < 8; ++j) val[j] = (short)f2bf(xv[j]);
      }
      int slot = c8 ^ (row & 7);
      *reinterpret_cast<s16x8*>(&lds_a[row * 64 + slot * 8]) = val;
    }
    __syncthreads();

    s16x8 af[2][2];
#pragma unroll
    for (int mi = 0; mi < 2; ++mi)
#pragma unroll
      for (int kh = 0; kh < 2; ++kh) {
        int row = w * 32 + mi * 16 + lc;
        int slot = (kh * 4 + lr) ^ (row & 7);
        af[mi][kh] = *reinterpret_cast<const s16x8*>(&lds_a[row * 64 + slot * 8]);
      }
#pragma unroll
    for (int kh = 0; kh < 2; ++kh)
#pragma unroll
      for (int nf = 0; nf < 4; ++nf) {
        s16x8 bf = *reinterpret_cast<const s16x8*>(&lds_b[(kh * 4 + nf) * 512 + l * 8]);
#pragma unroll
        for (int mi = 0; mi < 2; ++mi)
          acc[mi][nf] = __builtin_amdgcn_mfma_f32_16x16x32_bf16(
              af[mi][kh], bf, acc[mi][nf], 0, 0, 0);
      }
  }

  float bias_l[4];
#pragma unroll
  for (int nf = 0; nf < 4; ++nf) bias_l[nf] = bias[nf * 16 + lc];

  __syncthreads();  // frag reads done; reuse lds_a for bf16 result tile
#pragma unroll
  for (int mi = 0; mi < 2; ++mi)
#pragma unroll
    for (int r = 0; r < 4; ++r) {
      int row = w * 32 + mi * 16 + lr * 4 + r;
      int grow = row0 + row;
      if (grow < NN) {
#pragma unroll
        for (int nf = 0; nf < 4; ++nf) {
          float v = acc[mi][nf][r] + bias_l[nf];
          ushort bv = f2bf(v);
          int col = nf * 16 + lc;
          hbf[(size_t)grow * HD + col] = bv;
          lds_a[row * 64 + ((col >> 3) ^ (row & 7)) * 8 + (col & 7)] = bv;
        }
      }
    }
  __syncthreads();

  // pooling from the LDS tile (graph-boundary flush + atomics)
  int c = tid & 63, rg = tid >> 6;
  int rend = row0 + 128 < NN ? row0 + 128 : NN;
  int rstart = row0 + rg;
  int cur = gid[rstart < NN ? rstart : NN - 1];
  float pacc = 0.f;
  for (int r = rstart; r < rend; r += 4) {
    int g = gid[r];
    if (g != cur) {
      atomicAdd(&pooled0[cur * HD + c], pacc);
      pacc = 0.f;
      cur = g;
    }
    int lrow = r - row0;
    pacc += bf2f(lds_a[lrow * 64 + ((c >> 3) ^ (lrow & 7)) * 8 + (c & 7)]);
  }
  atomicAdd(&pooled0[cur * HD + c], pacc);
}

// ---------------- MFMA GEMM (layer modes) -----------------------------------
// MODE 1: WAVE-OWNED fused gather (coarsely src-sorted neighbor lists ->
//         L2 sliding window): a = (1+eps)*hbf[v] + sum hbf[u];
//         t1bf = bf16(a @ W1 + b1) ; f32 stats -> bn_out
// MODE 2: staging = relu(bn1(t1bf)); t = staging @ W2 + b2; t *= snorm
//         t1bf (in-place) = bf16(t) ; f32 stats -> bn_out
template <int MODE, int MR, int BLK>
__global__ __launch_bounds__(BLK, 4) void gemm_kernel(
    const void* Xin, const ushort* __restrict__ wt,
    const float* __restrict__ bias, const float* __restrict__ bn_in,
    const float* __restrict__ g1p, const float* __restrict__ be1p,
    const float* __restrict__ snorm, const int* __restrict__ rp,
    const int* __restrict__ csrc, const float* __restrict__ eps_p,
    ushort* __restrict__ outbf, float* __restrict__ bn_out) {
  constexpr int NWAVE = BLK / 64;
  constexpr int WR = MR / NWAVE;  // rows per wave
  constexpr int MI = WR / 16;     // m-frags per wave
  __shared__ ushort lds_a[MR * 64];  // row-major, 16B-chunk XOR swizzle
  __shared__ ushort lds_b[4096];     // fragment-packed
  __shared__ float lds_red[2][NWAVE][64];
  __shared__ float lds_bn[2][64];

  const int tid = threadIdx.x;
  const int row0 = blockIdx.x * MR;
  const int w = tid >> 6;
  const int l = tid & 63;
  const int lr = l >> 4, lc = l & 15;

  if (MODE == 2) {
    if (tid < 64) {
      float s = bn_in[tid], q = bn_in[64 + tid];
      float m = s * (1.0f / NN);
      float r = rsqrtf(q * (1.0f / NN) - m * m + 1e-5f);
      float scl = g1p[tid] * r;
      lds_bn[0][tid] = scl;
      lds_bn[1][tid] = be1p[tid] - m * scl;
    }
    __syncthreads();
  }

  f32x4 acc[MI][4];
#pragma unroll
  for (int mi = 0; mi < MI; ++mi)
#pragma unroll
    for (int nf = 0; nf < 4; ++nf)
#pragma unroll
      for (int r = 0; r < 4; ++r) acc[mi][nf][r] = 0.f;

  // stage B (linear copy of pre-packed weights)
#pragma unroll
  for (int i = 0; i < 512 / BLK; ++i) {
    int ch = i * BLK + tid;
    *reinterpret_cast<s16x8*>(&lds_b[ch * 8]) =
        *reinterpret_cast<const s16x8*>(&wt[ch * 8]);
  }

  if (MODE == 1) {
    __shared__ int lds_idx[MAXIDX];
    const ushort* hbf = reinterpret_cast<const ushort*>(Xin);
    float epsv = 1.0f + eps_p[0];
    int lane = tid & 7;
    // stage this tile's contiguous edge-index slab into LDS
    int rhigh = row0 + MR < NN ? row0 + MR : NN;
    int ebeg = rp[row0];
    int ecnt = rp[rhigh] - ebeg;
    int estg = ecnt < MAXIDX ? ecnt : MAXIDX;
    for (int i = tid; i < estg; i += BLK) lds_idx[i] = csrc[ebeg + i];
    __syncthreads();  // B + idx slab ready; no barrier after this
    // wave-owned gather: wave w produces rows [w*WR, w*WR+WR)
#pragma unroll
    for (int g = 0; g < WR / 8; ++g) {
      int row = w * WR + g * 8 + (l >> 3);
      int grow = row0 + row;
      s16x8 val = zero8();
      if (grow < NN) {
        int beg = rp[grow], end = rp[grow + 1];
        bool uselds = (end - ebeg) <= MAXIDX;
        f4 sv = *reinterpret_cast<const f4*>(&hbf[(size_t)grow * HD + lane * 8]);
        const ushort* su = reinterpret_cast<const ushort*>(&sv);
        float a8[8];
#pragma unroll
        for (int j = 0; j < 8; ++j) a8[j] = epsv * bf2f(su[j]);
        int e = beg;
#define EIDX(ee) (uselds ? lds_idx[(ee)-ebeg] : csrc[(ee)])
#define ROWLD(ee) \
  (*reinterpret_cast<const f4*>(&hbf[(size_t)EIDX(ee) * HD + lane * 8]))
        if (e + 1 < end) {
          f4 c0 = ROWLD(e), c1 = ROWLD(e + 1);
          e += 2;
          while (e + 1 < end) {
            f4 n0 = ROWLD(e), n1 = ROWLD(e + 1);
            e += 2;
            const ushort* u0 = reinterpret_cast<const ushort*>(&c0);
            const ushort* u1 = reinterpret_cast<const ushort*>(&c1);
#pragma unroll
            for (int j = 0; j < 8; ++j) a8[j] += bf2f(u0[j]) + bf2f(u1[j]);
            c0 = n0;
            c1 = n1;
          }
          const ushort* u0 = reinterpret_cast<const ushort*>(&c0);
          const ushort* u1 = reinterpret_cast<const ushort*>(&c1);
#pragma unroll
          for (int j = 0; j < 8; ++j) a8[j] += bf2f(u0[j]) + bf2f(u1[j]);
        }
        if (e < end) {
          f4 v0 = ROWLD(e);
          const ushort* u0 = reinterpret_cast<const ushort*>(&v0);
#pragma unroll
          for (int j = 0; j < 8; ++j) a8[j] += bf2f(u0[j]);
        }
#undef ROWLD
#undef EIDX
#pragma unroll
        for (int j = 0; j < 8; ++j) val[j] = (short)f2bf(a8[j]);
      }
      int slot = lane ^ (row & 7);
      *reinterpret_cast<s16x8*>(&lds_a[row * 64 + slot * 8]) = val;
    }
    // no __syncthreads: wave reads only its own rows
  } else {
#pragma unroll
    for (int i = 0; i < MR * 8 / BLK; ++i) {
      int f8i = i * BLK + tid;
      int row = f8i >> 3, c8 = f8i & 7;
      int grow = row0 + row;
      s16x8 val = zero8();
      if (grow < NN) {
        s16x8 raw = *reinterpret_cast<const s16x8*>(
            reinterpret_cast<const ushort*>(Xin) + (size_t)grow * HD + c8 * 8);
#pragma unroll
        for (int j = 0; j < 8; ++j) {
          int c = c8 * 8 + j;
          float v = bf2f((ushort)raw[j]) * lds_bn[0][c] + lds_bn[1][c];
          v = v > 0.f ? v : 0.f;
          val[j] = (short)f2bf(v);
        }
      }
      int slot = c8 ^ (row & 7);
      *reinterpret_cast<s16x8*>(&lds_a[row * 64 + slot * 8]) = val;
    }
    __syncthreads();  // cross-wave staging -> barrier required
  }

  s16x8 af[MI][2];
#pragma unroll
  for (int mi = 0; mi < MI; ++mi)
#pragma unroll
    for (int kh = 0; kh < 2; ++kh) {
      int row = w * WR + mi * 16 + lc;
      int slot = (kh * 4 + lr) ^ (row & 7);
      af[mi][kh] = *reinterpret_cast<const s16x8*>(&lds_a[row * 64 + slot * 8]);
    }
#pragma unroll
  for (int kh = 0; kh < 2; ++kh)
#pragma unroll
    for (int nf = 0; nf < 4; ++nf) {
      s16x8 bf = *reinterpret_cast<const s16x8*>(&lds_b[(kh * 4 + nf) * 512 + l * 8]);
#pragma unroll
      for (int mi = 0; mi < MI; ++mi)
        acc[mi][nf] = __builtin_amdgcn_mfma_f32_16x16x32_bf16(
            af[mi][kh], bf, acc[mi][nf], 0, 0, 0);
    }

  // epilogue: D lane l reg r -> row=(l>>4)*4+r, col=l&15
  float bias_l[4];
#pragma unroll
  for (int nf = 0; nf < 4; ++nf) bias_l[nf] = bias[nf * 16 + lc];

  float psum[4] = {0.f, 0.f, 0.f, 0.f}, psq[4] = {0.f, 0.f, 0.f, 0.f};
#pragma unroll
  for (int mi = 0; mi < MI; ++mi)
#pragma unroll
    for (int r = 0; r < 4; ++r) {
      int grow = row0 + w * WR + mi * 16 + lr * 4 + r;
      if (grow < NN) {
        float sn = (MODE == 2) ? snorm[grow] : 1.0f;
#pragma unroll
        for (int nf = 0; nf < 4; ++nf) {
          float v = acc[mi][nf][r] + bias_l[nf];
          if (MODE == 2) v *= sn;
          outbf[(size_t)grow * HD + nf * 16 + lc] = f2bf(v);
          psum[nf] += v;
          psq[nf] += v * v;
        }
      }
    }
#pragma unroll
  for (int nf = 0; nf < 4; ++nf) {
    psum[nf] += __shfl_xor(psum[nf], 16);
    psq[nf] += __shfl_xor(psq[nf], 16);
    psum[nf] += __shfl_xor(psum[nf], 32);
    psq[nf] += __shfl_xor(psq[nf], 32);
  }
  if (l < 16) {
#pragma unroll
    for (int nf = 0; nf < 4; ++nf) {
      lds_red[0][w][nf * 16 + l] = psum[nf];
      lds_red[1][w][nf * 16 + l] = psq[nf];
    }
  }
  __syncthreads();
  if (tid < 64) {
    float s = 0.f, q = 0.f;
#pragma unroll
    for (int w2 = 0; w2 < NWAVE; ++w2) {
      s += lds_red[0][w2][tid];
      q += lds_red[1][w2][tid];
    }
    atomicAdd(&bn_out[tid], s);
    atomicAdd(&bn_out[64 + tid], q);
  }
}

// --- fused layer tail: h_bf = bf16(h + relu(bn2(t2))); pool (fp32 acc) ------
__global__ __launch_bounds__(256) void final_pool_kernel(
    const ushort* __restrict__ t2bf, ushort* __restrict__ hbf,
    const float* __restrict__ g2p, const float* __restrict__ be2p,
    const float* __restrict__ stats2, const int* __restrict__ gid,
    float* __restrict__ pooledL) {
  int tid = threadIdx.x;
  int c = tid & 63;
  int rg = tid >> 6;
  float s = stats2[c], q = stats2[64 + c];
  float m = s * (1.0f / NN);
  float rr = rsqrtf(q * (1.0f / NN) - m * m + 1e-5f);
  float scl = g2p[c] * rr;
  float shv = be2p[c] - m * scl;
  int r0 = blockIdx.x * 128;
  int rend = r0 + 128 < NN ? r0 + 128 : NN;
  int rstart = r0 + rg;
  int cur = gid[rstart < NN ? rstart : NN - 1];
  float pacc = 0.f;
  for (int r = rstart; r < rend; r += 4) {
    int g = gid[r];
    if (g != cur) {
      atomicAdd(&pooledL[cur * HD + c], pacc);
      pacc = 0.f;
      cur = g;
    }
    float v = bf2f(t2bf[(size_t)r * HD + c]) * scl + shv;
    v = v > 0.f ? v : 0.f;
    float nv = bf2f(hbf[(size_t)r * HD + c]) + v;
    hbf[(size_t)r * HD + c] = f2bf(nv);
    pacc += nv;
  }
  atomicAdd(&pooledL[cur * HD + c], pacc);
}

// ---------------- final readout --------------------------------------------
__global__ __launch_bounds__(256) void score_kernel(
    const float* __restrict__ pooled, const float* __restrict__ Wlin,
    const float* __restrict__ blin, float* __restrict__ out) {
  int o = blockIdx.x * 256 + threadIdx.x;
  if (o >= NG * NC) return;
  int g = o / NC, c = o % NC;
  float s = 0.f;
  for (int i = 0; i <= NL; ++i) {
    s += blin[i * NC + c];
    const float* pg = &pooled[i * NG * HD + g * HD];
    const float* wl = &Wlin[i * HD * NC + c];
    float acc = 0.f;
#pragma unroll 8
    for (int k = 0; k < HD; ++k) acc += pg[k] * wl[k * NC];
    s += acc;
  }
  out[o] = s;
}

extern "C" void kernel_launch(void* const* d_in, const int* in_sizes, int n_in,
                              void* d_out, int out_size, void* d_ws,
                              size_t ws_size, hipStream_t stream) {
  const float* X = (const float*)d_in[0];
  const float* snorm = (const float*)d_in[1];
  const int* src = (const int*)d_in[2];
  const int* dst = (const int*)d_in[3];
  const int* gid = (const int*)d_in[4];
  const float* W_embed = (const float*)d_in[5];
  const float* b_embed = (const float*)d_in[6];
  const float* eps = (const float*)d_in[7];
  const float* W1 = (const float*)d_in[8];
  const float* b1 = (const float*)d_in[9];
  const float* g1 = (const float*)d_in[10];
  const float* be1 = (const float*)d_in[11];
  const float* W2 = (const float*)d_in[12];
  const float* b2 = (const float*)d_in[13];
  const float* g2 = (const float*)d_in[14];
  const float* be2 = (const float*)d_in[15];
  const float* Wlin = (const float*)d_in[16];
  const float* blin = (const float*)d_in[17];

  float* ws = (float*)d_ws;
  float* scratch = ws;                        // N*64 f32 (pairs overlay in build)
  float* pooled = scratch + (size_t)NN * HD;  // 5*200*64
  float* stats = pooled + 5 * NG * HD;        // NL*256: {bn1 s,q | bn2 s,q}
  int* gbucket = (int*)(stats + NL * 256);    // 256 (196 used) -- in zero span
  int* ib = gbucket + 256;
  int* row_ptr = ib;                          // 100004
  int* bbase = ib + 100004;                   // 200
  int* bcur = ib + 100204;                    // 196
  int* csr_src = ib + 100400;                 // NE
  ushort* h_bf = (ushort*)(ib + 100400 + NE);  // N*64 bf16
  ushort* t1bf = h_bf + (size_t)NN * HD;       // N*64 bf16 (t1 and t2 in-place)
  ushort* Wpk = t1bf + (size_t)NN * HD;        // 10*4096 bf16
  int2* pairs = (int2*)scratch;

  const int GRID128 = (NN + 127) / 128;  // 782
  const int EBLK = (NE + 4095) / 4096;   // 391

  // prologue: pack weights + zero pooled/stats/gbucket (one kernel)
  prologue_kernel<<<26, 256, 0, stream>>>(W_embed, W1, W2, Wpk, pooled);

  bucket_hist<<<EBLK, 256, 0, stream>>>(dst, gbucket);
  bucket_scan<<<1, 256, 0, stream>>>(gbucket, bbase, bcur);
  bucket_scatter<<<EBLK, 256, 0, stream>>>(src, dst, bcur, pairs);
  csr_build<<<NBKT, 256, 0, stream>>>(pairs, bbase, row_ptr, csr_src);

  embed_kernel<<<GRID128, 256, 0, stream>>>(X, Wpk, b_embed, gid, h_bf,
                                            pooled);

  for (int l = 0; l < NL; ++l) {
    float* st1 = stats + l * 256;        // bn1 sum/sumsq
    float* st2 = stats + l * 256 + 128;  // bn2 sum/sumsq
    // gemm1: wave-owned fused gather over coarsely src-sorted adjacency
    gemm_kernel<1, 128, 512><<<GRID128, 512, 0, stream>>>(
        h_bf, Wpk + (2 + l) * 4096, b1 + l * 64, nullptr, nullptr, nullptr,
        nullptr, row_ptr, csr_src, eps + l, t1bf, st1);
    // gemm2: BN1+ReLU on staging, in-place t1bf -> t2
    gemm_kernel<2, 128, 256><<<GRID128, 256, 0, stream>>>(
        t1bf, Wpk + (6 + l) * 4096, b2 + l * 64, st1, g1 + l * 64,
        be1 + l * 64, snorm, nullptr, nullptr, nullptr, t1bf, st2);
    final_pool_kernel<<<GRID128, 256, 0, stream>>>(
        t1bf, h_bf, g2 + l * 64, be2 + l * 64, st2, gid,
        pooled + (l + 1) * NG * HD);
  }

  score_kernel<<<(NG * NC + 255) / 256, 256, 0, stream>>>(pooled, Wlin, blin,
                                                          (float*)d_out);
}

// Round 22
// 541.459 us; speedup vs baseline: 1.0334x; 1.0334x over previous
//
#include <hip/hip_runtime.h>
#include <hip/hip_bf16.h>
#include <math.h>

#define NN 100000
#define NE 1600000
#define KIN 128
#define HD 64
#define NC 10
#define NL 4
#define NG 200
#define NBKT 196     // buckets of 512 nodes: bucket = dst >> 9
#define MAXIDX 2560  // LDS edge-index slab (gather)
#define SORTCAP 12288  // LDS sort buffer (mean 8192/bucket, +45 sigma)
#define SB 16        // coarse sort buckets (src>>13: 0..12 used)
#define ZCNT (5 * NG * HD + NL * 256 + 256)  // zero span (floats)

typedef short s16x8 __attribute__((ext_vector_type(8)));
typedef float f32x4 __attribute__((ext_vector_type(4)));
using f4 = float4;

static __device__ __forceinline__ ushort f2bf(float x) {
  __hip_bfloat16 b = __float2bfloat16(x);
  return *reinterpret_cast<ushort*>(&b);
}
static __device__ __forceinline__ float bf2f(ushort u) {
  return __uint_as_float(((unsigned)u) << 16);
}
static __device__ __forceinline__ s16x8 zero8() {
  s16x8 v;
#pragma unroll
  for (int i = 0; i < 8; ++i) v[i] = 0;
  return v;
}

// ---------- prologue: pack weights (blocks 0-9) + zero accum (blocks 10+) ---
__global__ __launch_bounds__(256) void prologue_kernel(
    const float* __restrict__ Wemb, const float* __restrict__ W1,
    const float* __restrict__ W2, ushort* __restrict__ Wpk,
    float* __restrict__ zbase) {
  int b = blockIdx.x;
  if (b < 10) {
    const float* src = (b < 2)   ? Wemb + b * 4096
                       : (b < 6) ? W1 + (b - 2) * 4096
                                 : W2 + (b - 6) * 4096;
    for (int idx = threadIdx.x; idx < 4096; idx += 256) {
      int k = idx >> 6, n = idx & 63;
      int dsti = ((k >> 5) * 4 + (n >> 4)) * 512 +
                 (((k >> 3) & 3) * 16 + (n & 15)) * 8 + (k & 7);
      Wpk[b * 4096 + dsti] = f2bf(src[idx]);
    }
  } else {
    int nz = (gridDim.x - 10) * 256;
    f4 z = make_float4(0.f, 0.f, 0.f, 0.f);
    for (int i = (b - 10) * 256 + threadIdx.x; i < ZCNT / 4; i += nz)
      *reinterpret_cast<f4*>(&zbase[i * 4]) = z;
  }
}

// ======================= CSR build via 2-level counting sort ================
__global__ __launch_bounds__(256) void bucket_hist(const int* __restrict__ dst,
                                                   int* __restrict__ gbucket) {
  __shared__ int lh[NBKT];
  int tid = threadIdx.x;
  for (int i = tid; i < NBKT; i += 256) lh[i] = 0;
  __syncthreads();
  int base = blockIdx.x * 4096;
#pragma unroll 4
  for (int it = 0; it < 16; ++it) {
    int e = base + it * 256 + tid;
    if (e < NE) atomicAdd(&lh[dst[e] >> 9], 1);
  }
  __syncthreads();
  for (int i = tid; i < NBKT; i += 256)
    if (lh[i]) atomicAdd(&gbucket[i], lh[i]);
}

__global__ __launch_bounds__(256) void bucket_scan(const int* __restrict__ gbucket,
                                                   int* __restrict__ bbase,
                                                   int* __restrict__ bcur) {
  __shared__ int s[256];
  int tid = threadIdx.x;
  int v = (tid < NBKT) ? gbucket[tid] : 0;
  s[tid] = v;
  __syncthreads();
  for (int off = 1; off < 256; off <<= 1) {
    int t = (tid >= off) ? s[tid - off] : 0;
    __syncthreads();
    s[tid] += t;
    __syncthreads();
  }
  int excl = s[tid] - v;
  if (tid <= NBKT) bbase[tid] = excl;
  if (tid < NBKT) bcur[tid] = excl;
}

__global__ __launch_bounds__(256) void bucket_scatter(const int* __restrict__ src,
                                                      const int* __restrict__ dst,
                                                      int* __restrict__ bcur,
                                                      int2* __restrict__ pairs) {
  __shared__ int lh[NBKT];
  __shared__ int lbase[NBKT];
  int tid = threadIdx.x;
  for (int i = tid; i < NBKT; i += 256) lh[i] = 0;
  __syncthreads();
  int base = blockIdx.x * 4096;
  int dloc[16], sloc[16];
#pragma unroll
  for (int it = 0; it < 16; ++it) {
    int e = base + it * 256 + tid;
    bool ok = e < NE;
    dloc[it] = ok ? dst[e] : -1;
    sloc[it] = ok ? src[e] : 0;
    if (ok) atomicAdd(&lh[dloc[it] >> 9], 1);
  }
  __syncthreads();
  for (int i = tid; i < NBKT; i += 256) {
    int c = lh[i];
    lbase[i] = c ? atomicAdd(&bcur[i], c) : 0;
    lh[i] = 0;
  }
  __syncthreads();
#pragma unroll
  for (int it = 0; it < 16; ++it) {
    int d = dloc[it];
    if (d >= 0) {
      int b = d >> 9;
      int p = lbase[b] + atomicAdd(&lh[b], 1);
      pairs[p] = make_int2(d, sloc[it]);
    }
  }
}

// builds row_ptr/csr_src; neighbor lists COARSELY sorted by src>>13 via
// per-row counting sort (register counters, O(d) passes, no dep chains).
__global__ __launch_bounds__(256) void csr_build(const int2* __restrict__ pairs,
                                                 const int* __restrict__ bbase,
                                                 int* __restrict__ row_ptr,
                                                 int* __restrict__ csr_src) {
  __shared__ int deg[512];
  __shared__ int psum[256];
  __shared__ int cur[512];
  __shared__ int srt[SORTCAP];
  int b = blockIdx.x;
  int tid = threadIdx.x;
  int beg = bbase[b], end = bbase[b + 1];
  int cnt = end - beg;
  int node0 = b << 9;
  deg[tid] = 0;
  deg[tid + 256] = 0;
  __syncthreads();
  for (int i = beg + tid; i < end; i += 256)
    atomicAdd(&deg[pairs[i].x - node0], 1);
  __syncthreads();
  int a0 = deg[2 * tid], a1 = deg[2 * tid + 1];
  psum[tid] = a0 + a1;
  __syncthreads();
  for (int off = 1; off < 256; off <<= 1) {
    int t = (tid >= off) ? psum[tid - off] : 0;
    __syncthreads();
    psum[tid] += t;
    __syncthreads();
  }
  int pe = psum[tid] - (a0 + a1);
  int e0 = pe, e1 = pe + a0;  // local (beg-relative) row starts
  cur[2 * tid] = e0;
  cur[2 * tid + 1] = e1;
  int n0 = node0 + 2 * tid, n1 = node0 + 2 * tid + 1;
  if (n0 < NN) row_ptr[n0] = beg + e0;
  if (n1 < NN) row_ptr[n1] = beg + e1;
  __syncthreads();

  if (cnt <= SORTCAP) {
    // scatter into LDS (local positions)
    for (int i = beg + tid; i < end; i += 256) {
      int2 pr = pairs[i];
      int p = atomicAdd(&cur[pr.x - node0], 1);
      srt[p] = pr.y;
    }
    __syncthreads();
    // coarse counting sort per owned row: bucket = src>>13 (1MB granularity)
#pragma unroll
    for (int rr = 0; rr < 2; ++rr) {
      int s0 = (rr == 0) ? e0 : e1;
      int d0 = (rr == 0) ? a0 : a1;
      int ofs[SB];
#pragma unroll
      for (int q = 0; q < SB; ++q) ofs[q] = 0;
      for (int i = 0; i < d0; ++i) {
        int bkt = srt[s0 + i] >> 13;
#pragma unroll
        for (int q = 0; q < SB; ++q) ofs[q] += (bkt == q) ? 1 : 0;
      }
      // exclusive prefix in registers
      int run = 0;
#pragma unroll
      for (int q = 0; q < SB; ++q) {
        int c = ofs[q];
        ofs[q] = run;
        run += c;
      }
      // stable placement (direct to global)
      for (int i = 0; i < d0; ++i) {
        int key = srt[s0 + i];
        int bkt = key >> 13;
        int pos = 0;
#pragma unroll
        for (int q = 0; q < SB; ++q)
          if (bkt == q) pos = ofs[q];
        csr_src[beg + s0 + pos] = key;
#pragma unroll
        for (int q = 0; q < SB; ++q) ofs[q] += (bkt == q) ? 1 : 0;
      }
    }
  } else {
    // fallback (statistically unreachable): global scatter, unsorted
    for (int i = beg + tid; i < end; i += 256) {
      int2 pr = pairs[i];
      int p = atomicAdd(&cur[pr.x - node0], 1);
      csr_src[beg + p] = pr.y;
    }
  }
  if (b == 0 && tid == 0) row_ptr[NN] = NE;
}

// ------- embed GEMM + fused layer-0 pooling (pool from LDS tile) ------------
__global__ __launch_bounds__(256, 4) void embed_kernel(
    const float* __restrict__ X, const ushort* __restrict__ wt,
    const float* __restrict__ bias, const int* __restrict__ gid,
    ushort* __restrict__ hbf, float* __restrict__ pooled0) {
  __shared__ ushort lds_a[128 * 64];
  __shared__ ushort lds_b[4096];

  const int tid = threadIdx.x;
  const int row0 = blockIdx.x * 128;
  const int w = tid >> 6;
  const int l = tid & 63;
  const int lr = l >> 4, lc = l & 15;

  f32x4 acc[2][4];
#pragma unroll
  for (int mi = 0; mi < 2; ++mi)
#pragma unroll
    for (int nf = 0; nf < 4; ++nf)
#pragma unroll
      for (int r = 0; r < 4; ++r) acc[mi][nf][r] = 0.f;

  for (int kt = 0; kt < 2; ++kt) {
    if (kt) __syncthreads();
#pragma unroll
    for (int i = 0; i < 2; ++i) {
      int ch = i * 256 + tid;
      *reinterpret_cast<s16x8*>(&lds_b[ch * 8]) =
          *reinterpret_cast<const s16x8*>(&wt[kt * 4096 + ch * 8]);
    }
#pragma unroll
    for (int i = 0; i < 4; ++i) {
      int f8i = i * 256 + tid;
      int row = f8i >> 3, c8 = f8i & 7;
      int grow = row0 + row;
      s16x8 val = zero8();
      if (grow < NN) {
        const float* p = X + (size_t)grow * KIN + kt * 64 + c8 * 8;
        f4 x0 = *reinterpret_cast<const f4*>(p);
        f4 x1 = *reinterpret_cast<const f4*>(p + 4);
        float xv[8] = {x0.x, x0.y, x0.z, x0.w, x1.x, x1.y, x1.z, x1.w};
#pragma unroll
        for (int j = 0; j < 8; ++j) val[j] = (short)f2bf(xv[j]);
      }
      int slot = c8 ^ (row & 7);
      *reinterpret_cast<s16x8*>(&lds_a[row * 64 + slot * 8]) = val;
    }
    __syncthreads();

    s16x8 af[2][2];
#pragma unroll
    for (int mi = 0; mi < 2; ++mi)
#pragma unroll
      for (int kh = 0; kh < 2; ++kh) {
        int row = w * 32 + mi * 16 + lc;
        int slot = (kh * 4 + lr) ^ (row & 7);
        af[mi][kh] = *reinterpret_cast<const s16x8*>(&lds_a[row * 64 + slot * 8]);
      }
#pragma unroll
    for (int kh = 0; kh < 2; ++kh)
#pragma unroll
      for (int nf = 0; nf < 4; ++nf) {
        s16x8 bf = *reinterpret_cast<const s16x8*>(&lds_b[(kh * 4 + nf) * 512 + l * 8]);
#pragma unroll
        for (int mi = 0; mi < 2; ++mi)
          acc[mi][nf] = __builtin_amdgcn_mfma_f32_16x16x32_bf16(
              af[mi][kh], bf, acc[mi][nf], 0, 0, 0);
      }
  }

  float bias_l[4];
#pragma unroll
  for (int nf = 0; nf < 4; ++nf) bias_l[nf] = bias[nf * 16 + lc];

  __syncthreads();  // frag reads done; reuse lds_a for bf16 result tile
#pragma unroll
  for (int mi = 0; mi < 2; ++mi)
#pragma unroll
    for (int r = 0; r < 4; ++r) {
      int row = w * 32 + mi * 16 + lr * 4 + r;
      int grow = row0 + row;
      if (grow < NN) {
#pragma unroll
        for (int nf = 0; nf < 4; ++nf) {
          float v = acc[mi][nf][r] + bias_l[nf];
          ushort bv = f2bf(v);
          int col = nf * 16 + lc;
          hbf[(size_t)grow * HD + col] = bv;
          lds_a[row * 64 + ((col >> 3) ^ (row & 7)) * 8 + (col & 7)] = bv;
        }
      }
    }
  __syncthreads();

  // pooling from the LDS tile (graph-boundary flush + atomics)
  int c = tid & 63, rg = tid >> 6;
  int rend = row0 + 128 < NN ? row0 + 128 : NN;
  int rstart = row0 + rg;
  int cur = gid[rstart < NN ? rstart : NN - 1];
  float pacc = 0.f;
  for (int r = rstart; r < rend; r += 4) {
    int g = gid[r];
    if (g != cur) {
      atomicAdd(&pooled0[cur * HD + c], pacc);
      pacc = 0.f;
      cur = g;
    }
    int lrow = r - row0;
    pacc += bf2f(lds_a[lrow * 64 + ((c >> 3) ^ (lrow & 7)) * 8 + (c & 7)]);
  }
  atomicAdd(&pooled0[cur * HD + c], pacc);
}

// ---------------- MFMA GEMM (layer modes) -----------------------------------
// MODE 1: WAVE-OWNED fused gather (coarsely src-sorted neighbor lists ->
//         L2 sliding window): a = (1+eps)*hbf[v] + sum hbf[u];
//         t1bf = bf16(a @ W1 + b1) ; f32 stats -> bn_out
// MODE 2: staging = relu(bn1(t1bf)); t = staging @ W2 + b2; t *= snorm
//         t1bf (in-place) = bf16(t) ; f32 stats -> bn_out
template <int MODE, int MR, int BLK>
__global__ __launch_bounds__(BLK, 4) void gemm_kernel(
    const void* Xin, const ushort* __restrict__ wt,
    const float* __restrict__ bias, const float* __restrict__ bn_in,
    const float* __restrict__ g1p, const float* __restrict__ be1p,
    const float* __restrict__ snorm, const int* __restrict__ rp,
    const int* __restrict__ csrc, const float* __restrict__ eps_p,
    ushort* __restrict__ outbf, float* __restrict__ bn_out) {
  constexpr int NWAVE = BLK / 64;
  constexpr int WR = MR / NWAVE;  // rows per wave
  constexpr int MI = WR / 16;     // m-frags per wave
  __shared__ ushort lds_a[MR * 64];  // row-major, 16B-chunk XOR swizzle
  __shared__ ushort lds_b[4096];     // fragment-packed
  __shared__ float lds_red[2][NWAVE][64];
  __shared__ float lds_bn[2][64];

  const int tid = threadIdx.x;
  const int row0 = blockIdx.x * MR;
  const int w = tid >> 6;
  const int l = tid & 63;
  const int lr = l >> 4, lc = l & 15;

  if (MODE == 2) {
    if (tid < 64) {
      float s = bn_in[tid], q = bn_in[64 + tid];
      float m = s * (1.0f / NN);
      float r = rsqrtf(q * (1.0f / NN) - m * m + 1e-5f);
      float scl = g1p[tid] * r;
      lds_bn[0][tid] = scl;
      lds_bn[1][tid] = be1p[tid] - m * scl;
    }
    __syncthreads();
  }

  f32x4 acc[MI][4];
#pragma unroll
  for (int mi = 0; mi < MI; ++mi)
#pragma unroll
    for (int nf = 0; nf < 4; ++nf)
#pragma unroll
      for (int r = 0; r < 4; ++r) acc[mi][nf][r] = 0.f;

  // stage B (linear copy of pre-packed weights)
#pragma unroll
  for (int i = 0; i < 512 / BLK; ++i) {
    int ch = i * BLK + tid;
    *reinterpret_cast<s16x8*>(&lds_b[ch * 8]) =
        *reinterpret_cast<const s16x8*>(&wt[ch * 8]);
  }

  if (MODE == 1) {
    __shared__ int lds_idx[MAXIDX];
    const ushort* hbf = reinterpret_cast<const ushort*>(Xin);
    float epsv = 1.0f + eps_p[0];
    int lane = tid & 7;
    // stage this tile's contiguous edge-index slab into LDS
    int rhigh = row0 + MR < NN ? row0 + MR : NN;
    int ebeg = rp[row0];
    int ecnt = rp[rhigh] - ebeg;
    int estg = ecnt < MAXIDX ? ecnt : MAXIDX;
    for (int i = tid; i < estg; i += BLK) lds_idx[i] = csrc[ebeg + i];
    __syncthreads();  // B + idx slab ready; no barrier after this
    // wave-owned gather: wave w produces rows [w*WR, w*WR+WR)
#pragma unroll
    for (int g = 0; g < WR / 8; ++g) {
      int row = w * WR + g * 8 + (l >> 3);
      int grow = row0 + row;
      s16x8 val = zero8();
      if (grow < NN) {
        int beg = rp[grow], end = rp[grow + 1];
        bool uselds = (end - ebeg) <= MAXIDX;
        f4 sv = *reinterpret_cast<const f4*>(&hbf[(size_t)grow * HD + lane * 8]);
        const ushort* su = reinterpret_cast<const ushort*>(&sv);
        float a8[8];
#pragma unroll
        for (int j = 0; j < 8; ++j) a8[j] = epsv * bf2f(su[j]);
        int e = beg;
#define EIDX(ee) (uselds ? lds_idx[(ee)-ebeg] : csrc[(ee)])
#define ROWLD(ee) \
  (*reinterpret_cast<const f4*>(&hbf[(size_t)EIDX(ee) * HD + lane * 8]))
        if (e + 1 < end) {
          f4 c0 = ROWLD(e), c1 = ROWLD(e + 1);
          e += 2;
          while (e + 1 < end) {
            f4 n0 = ROWLD(e), n1 = ROWLD(e + 1);
            e += 2;
            const ushort* u0 = reinterpret_cast<const ushort*>(&c0);
            const ushort* u1 = reinterpret_cast<const ushort*>(&c1);
#pragma unroll
            for (int j = 0; j < 8; ++j) a8[j] += bf2f(u0[j]) + bf2f(u1[j]);
            c0 = n0;
            c1 = n1;
          }
          const ushort* u0 = reinterpret_cast<const ushort*>(&c0);
          const ushort* u1 = reinterpret_cast<const ushort*>(&c1);
#pragma unroll
          for (int j = 0; j < 8; ++j) a8[j] += bf2f(u0[j]) + bf2f(u1[j]);
        }
        if (e < end) {
          f4 v0 = ROWLD(e);
          const ushort* u0 = reinterpret_cast<const ushort*>(&v0);
#pragma unroll
          for (int j = 0; j < 8; ++j) a8[j] += bf2f(u0[j]);
        }
#undef ROWLD
#undef EIDX
#pragma unroll
        for (int j = 0; j < 8; ++j) val[j] = (short)f2bf(a8[j]);
      }
      int slot = lane ^ (row & 7);
      *reinterpret_cast<s16x8*>(&lds_a[row * 64 + slot * 8]) = val;
    }
    // no __syncthreads: wave reads only its own rows
  } else {
#pragma unroll
    for (int i = 0; i < MR * 8 / BLK; ++i) {
      int f8i = i * BLK + tid;
      int row = f8i >> 3, c8 = f8i & 7;
      int grow = row0 + row;
      s16x8 val = zero8();
      if (grow < NN) {
        s16x8 raw = *reinterpret_cast<const s16x8*>(
            reinterpret_cast<const ushort*>(Xin) + (size_t)grow * HD + c8 * 8);
#pragma unroll
        for (int j = 0; j < 8; ++j) {
          int c = c8 * 8 + j;
          float v = bf2f((ushort)raw[j]) * lds_bn[0][c] + lds_bn[1][c];
          v = v > 0.f ? v : 0.f;
          val[j] = (short)f2bf(v);
        }
      }
      int slot = c8 ^ (row & 7);
      *reinterpret_cast<s16x8*>(&lds_a[row * 64 + slot * 8]) = val;
    }
    __syncthreads();  // cross-wave staging -> barrier required
  }

  s16x8 af[MI][2];
#pragma unroll
  for (int mi = 0; mi < MI; ++mi)
#pragma unroll
    for (int kh = 0; kh < 2; ++kh) {
      int row = w * WR + mi * 16 + lc;
      int slot = (kh * 4 + lr) ^ (row & 7);
      af[mi][kh] = *reinterpret_cast<const s16x8*>(&lds_a[row * 64 + slot * 8]);
    }
#pragma unroll
  for (int kh = 0; kh < 2; ++kh)
#pragma unroll
    for (int nf = 0; nf < 4; ++nf) {
      s16x8 bf = *reinterpret_cast<const s16x8*>(&lds_b[(kh * 4 + nf) * 512 + l * 8]);
#pragma unroll
      for (int mi = 0; mi < MI; ++mi)
        acc[mi][nf] = __builtin_amdgcn_mfma_f32_16x16x32_bf16(
            af[mi][kh], bf, acc[mi][nf], 0, 0, 0);
    }

  // epilogue: D lane l reg r -> row=(l>>4)*4+r, col=l&15
  float bias_l[4];
#pragma unroll
  for (int nf = 0; nf < 4; ++nf) bias_l[nf] = bias[nf * 16 + lc];

  float psum[4] = {0.f, 0.f, 0.f, 0.f}, psq[4] = {0.f, 0.f, 0.f, 0.f};
#pragma unroll
  for (int mi = 0; mi < MI; ++mi)
#pragma unroll
    for (int r = 0; r < 4; ++r) {
      int grow = row0 + w * WR + mi * 16 + lr * 4 + r;
      if (grow < NN) {
        float sn = (MODE == 2) ? snorm[grow] : 1.0f;
#pragma unroll
        for (int nf = 0; nf < 4; ++nf) {
          float v = acc[mi][nf][r] + bias_l[nf];
          if (MODE == 2) v *= sn;
          outbf[(size_t)grow * HD + nf * 16 + lc] = f2bf(v);
          psum[nf] += v;
          psq[nf] += v * v;
        }
      }
    }
#pragma unroll
  for (int nf = 0; nf < 4; ++nf) {
    psum[nf] += __shfl_xor(psum[nf], 16);
    psq[nf] += __shfl_xor(psq[nf], 16);
    psum[nf] += __shfl_xor(psum[nf], 32);
    psq[nf] += __shfl_xor(psq[nf], 32);
  }
  if (l < 16) {
#pragma unroll
    for (int nf = 0; nf < 4; ++nf) {
      lds_red[0][w][nf * 16 + l] = psum[nf];
      lds_red[1][w][nf * 16 + l] = psq[nf];
    }
  }
  __syncthreads();
  if (tid < 64) {
    float s = 0.f, q = 0.f;
#pragma unroll
    for (int w2 = 0; w2 < NWAVE; ++w2) {
      s += lds_red[0][w2][tid];
      q += lds_red[1][w2][tid];
    }
    atomicAdd(&bn_out[tid], s);
    atomicAdd(&bn_out[64 + tid], q);
  }
}

// --- fused layer tail: h_bf = bf16(h + relu(bn2(t2))); pool (fp32 acc) ------
__global__ __launch_bounds__(256) void final_pool_kernel(
    const ushort* __restrict__ t2bf, ushort* __restrict__ hbf,
    const float* __restrict__ g2p, const float* __restrict__ be2p,
    const float* __restrict__ stats2, const int* __restrict__ gid,
    float* __restrict__ pooledL) {
  int tid = threadIdx.x;
  int c = tid & 63;
  int rg = tid >> 6;
  float s = stats2[c], q = stats2[64 + c];
  float m = s * (1.0f / NN);
  float rr = rsqrtf(q * (1.0f / NN) - m * m + 1e-5f);
  float scl = g2p[c] * rr;
  float shv = be2p[c] - m * scl;
  int r0 = blockIdx.x * 128;
  int rend = r0 + 128 < NN ? r0 + 128 : NN;
  int rstart = r0 + rg;
  int cur = gid[rstart < NN ? rstart : NN - 1];
  float pacc = 0.f;
  for (int r = rstart; r < rend; r += 4) {
    int g = gid[r];
    if (g != cur) {
      atomicAdd(&pooledL[cur * HD + c], pacc);
      pacc = 0.f;
      cur = g;
    }
    float v = bf2f(t2bf[(size_t)r * HD + c]) * scl + shv;
    v = v > 0.f ? v : 0.f;
    float nv = bf2f(hbf[(size_t)r * HD + c]) + v;
    hbf[(size_t)r * HD + c] = f2bf(nv);
    pacc += nv;
  }
  atomicAdd(&pooledL[cur * HD + c], pacc);
}

// ---------------- final readout --------------------------------------------
__global__ __launch_bounds__(256) void score_kernel(
    const float* __restrict__ pooled, const float* __restrict__ Wlin,
    const float* __restrict__ blin, float* __restrict__ out) {
  int o = blockIdx.x * 256 + threadIdx.x;
  if (o >= NG * NC) return;
  int g = o / NC, c = o % NC;
  float s = 0.f;
  for (int i = 0; i <= NL; ++i) {
    s += blin[i * NC + c];
    const float* pg = &pooled[i * NG * HD + g * HD];
    const float* wl = &Wlin[i * HD * NC + c];
    float acc = 0.f;
#pragma unroll 8
    for (int k = 0; k < HD; ++k) acc += pg[k] * wl[k * NC];
    s += acc;
  }
  out[o] = s;
}

extern "C" void kernel_launch(void* const* d_in, const int* in_sizes, int n_in,
                              void* d_out, int out_size, void* d_ws,
                              size_t ws_size, hipStream_t stream) {
  const float* X = (const float*)d_in[0];
  const float* snorm = (const float*)d_in[1];
  const int* src = (const int*)d_in[2];
  const int* dst = (const int*)d_in[3];
  const int* gid = (const int*)d_in[4];
  const float* W_embed = (const float*)d_in[5];
  const float* b_embed = (const float*)d_in[6];
  const float* eps = (const float*)d_in[7];
  const float* W1 = (const float*)d_in[8];
  const float* b1 = (const float*)d_in[9];
  const float* g1 = (const float*)d_in[10];
  const float* be1 = (const float*)d_in[11];
  const float* W2 = (const float*)d_in[12];
  const float* b2 = (const float*)d_in[13];
  const float* g2 = (const float*)d_in[14];
  const float* be2 = (const float*)d_in[15];
  const float* Wlin = (const float*)d_in[16];
  const float* blin = (const float*)d_in[17];

  float* ws = (float*)d_ws;
  float* scratch = ws;                        // N*64 f32 (pairs overlay in build)
  float* pooled = scratch + (size_t)NN * HD;  // 5*200*64
  float* stats = pooled + 5 * NG * HD;        // NL*256: {bn1 s,q | bn2 s,q}
  int* gbucket = (int*)(stats + NL * 256);    // 256 (196 used) -- in zero span
  int* ib = gbucket + 256;
  int* row_ptr = ib;                          // 100004
  int* bbase = ib + 100004;                   // 200
  int* bcur = ib + 100204;                    // 196
  int* csr_src = ib + 100400;                 // NE
  ushort* h_bf = (ushort*)(ib + 100400 + NE);  // N*64 bf16
  ushort* t1bf = h_bf + (size_t)NN * HD;       // N*64 bf16 (t1 and t2 in-place)
  ushort* Wpk = t1bf + (size_t)NN * HD;        // 10*4096 bf16
  int2* pairs = (int2*)scratch;

  const int GRID128 = (NN + 127) / 128;  // 782
  const int EBLK = (NE + 4095) / 4096;   // 391

  // prologue: pack weights + zero pooled/stats/gbucket (one kernel)
  prologue_kernel<<<26, 256, 0, stream>>>(W_embed, W1, W2, Wpk, pooled);

  bucket_hist<<<EBLK, 256, 0, stream>>>(dst, gbucket);
  bucket_scan<<<1, 256, 0, stream>>>(gbucket, bbase, bcur);
  bucket_scatter<<<EBLK, 256, 0, stream>>>(src, dst, bcur, pairs);
  csr_build<<<NBKT, 256, 0, stream>>>(pairs, bbase, row_ptr, csr_src);

  embed_kernel<<<GRID128, 256, 0, stream>>>(X, Wpk, b_embed, gid, h_bf,
                                            pooled);

  for (int l = 0; l < NL; ++l) {
    float* st1 = stats + l * 256;        // bn1 sum/sumsq
    float* st2 = stats + l * 256 + 128;  // bn2 sum/sumsq
    // gemm1: wave-owned fused gather over coarsely src-sorted adjacency
    gemm_kernel<1, 128, 512><<<GRID128, 512, 0, stream>>>(
        h_bf, Wpk + (2 + l) * 4096, b1 + l * 64, nullptr, nullptr, nullptr,
        nullptr, row_ptr, csr_src, eps + l, t1bf, st1);
    // gemm2: BN1+ReLU on staging, in-place t1bf -> t2
    gemm_kernel<2, 128, 256><<<GRID128, 256, 0, stream>>>(
        t1bf, Wpk + (6 + l) * 4096, b2 + l * 64, st1, g1 + l * 64,
        be1 + l * 64, snorm, nullptr, nullptr, nullptr, t1bf, st2);
    final_pool_kernel<<<GRID128, 256, 0, stream>>>(
        t1bf, h_bf, g2 + l * 64, be2 + l * 64, st2, gid,
        pooled + (l + 1) * NG * HD);
  }

  score_kernel<<<(NG * NC + 255) / 256, 256, 0, stream>>>(pooled, Wlin, blin,
                                                          (float*)d_out);
}